// Round 19
// baseline (187.404 us; speedup 1.0000x reference)
//
#include <hip/hip_runtime.h>
#include <hip/hip_bf16.h>
#include <cstdint>
#include <cstddef>

// Pipeline (all convs MFMA; conv1 FUSED into conv2 -> c1p intermediate eliminated):
//   k_prep:   pad video -> pv[48,261,1056]bf16 | zero pad strips (pv,c2p) | repack w1/w2/w3
//   k_conv12: pv -> (3 conv1 rows in LDS, kh-interleaved, mt-split to avoid spill) -> c2p
//   k_convr<128,256,...>: c2p -> featb[48,32,32,256]bf16 (row-resident, barrier-free K-loop)
//   k_sample: bilinear q[1024,256]bf16
//   k_corrm:  LDS-staged MFMA corr + online softmax over 128-position chunks -> partials
//   k_merge:  combine 8 position-chunk partials -> pred/occl f32
//
// MFMA 16x16x32 bf16 layouts (verified):
//   A: lane l holds row=l&15,   k=(l>>4)*8+j  (bf16x8 contiguous)
//   B: lane l holds col=l&15,   k=(l>>4)*8+j
//   C: lane l holds col=l&15, row=(l>>4)*4+reg (f32x4)

typedef __attribute__((ext_vector_type(8))) short bf16x8;
typedef __attribute__((ext_vector_type(4))) float f32x4;

typedef const __attribute__((address_space(1))) void gv_t;   // global
typedef __attribute__((address_space(3))) void sv_t;         // LDS

__device__ __forceinline__ unsigned short bfr(float f) {
    return (unsigned short)(__bfloat16_as_ushort(__float2bfloat16(f)));
}

// ---------- fused prep: pad+cast video | zero pad strips (pv, c2p) | weight repacks ----------
__global__ __launch_bounds__(256) void k_prep(const float* __restrict__ video,
                                              const float* __restrict__ w1,
                                              const float* __restrict__ w2,
                                              const float* __restrict__ w3,
                                              __hip_bfloat16* __restrict__ pv,
                                              unsigned short* __restrict__ c2p,
                                              __hip_bfloat16* __restrict__ wp1,
                                              __hip_bfloat16* __restrict__ wp2,
                                              __hip_bfloat16* __restrict__ wp3)
{
    const int bid = blockIdx.x;
    if (bid < 12288) {
        const int iy = bid & 255;
        const int bt = bid >> 8;
        const int ix = threadIdx.x;
        const float* src = video + ((size_t)(bt * 256 + iy) * 256 + ix) * 3;
        unsigned* dst = (unsigned*)(pv + ((size_t)(bt * 261) + iy + 2) * 1056);
        const float v0 = src[0], v1 = src[1], v2 = src[2];
        const unsigned lo = (unsigned)bfr(v0) | ((unsigned)bfr(v1) << 16);
        const unsigned hi = (unsigned)bfr(v2);
        dst[(2 + ix) * 2 + 0] = lo;
        dst[(2 + ix) * 2 + 1] = hi;
        if (ix < 2)   { dst[ix * 2] = 0u; dst[ix * 2 + 1] = 0u; }
        if (ix >= 250){ dst[(ix + 8) * 2] = 0u; dst[(ix + 8) * 2 + 1] = 0u; }
    } else if (bid < 12288 + 4086) {
        const int i = (bid - 12288) * 256 + threadIdx.x;     // 1,046,016 total
        unsigned short* pvs = (unsigned short*)pv;
        if (i < 253440) {                                    // pv strips
            const int bt = i / 5280, rr = (i % 5280) / 1056, col = i % 1056;
            const int row = (rr < 2) ? rr : rr + 256;
            pvs[(size_t)(bt * 261 + row) * 1056 + col] = 0;
        } else {                                             // c2p strips: 48 x 16512
            const int j = i - 253440, bt = j / 16512, k = j % 16512;
            size_t addr;
            if (k < 8320) { const int px = k >> 7, c = k & 127;
                addr = ((size_t)(bt * 65 + 64) * 65 + px) * 128 + c; }
            else { const int k2 = k - 8320, row = k2 >> 7, c = k2 & 127;
                addr = ((size_t)(bt * 65 + row) * 65 + 64) * 128 + c; }
            c2p[addr] = 0;
        }
    } else {
        const int e = (bid - 12288 - 4086) * 256 + threadIdx.x;   // 382,976 total
        if (e < 14336) {
            const int j = e & 7, lane = (e >> 3) & 63, nt = (e >> 9) & 3, kh = e >> 11;
            const int k = ((lane >> 4) << 3) + j;
            const int kw = k >> 2, ci = k & 3;
            const int n = nt * 16 + (lane & 15);
            float v = (ci < 3 && kw < 7) ? w1[(size_t)((kh * 7 + kw) * 3 + ci) * 64 + n] : 0.f;
            wp1[e] = __float2bfloat16(v);
        } else if (e < 88064) {
            const int e2 = e - 14336;
            const int j = e2 & 7, lane = (e2 >> 3) & 63, nt = (e2 >> 9) & 7, ks = (e2 >> 12) & 1, tap = e2 >> 13;
            const int ci = ks * 32 + ((lane >> 4) << 3) + j;
            const int n  = nt * 16 + (lane & 15);
            wp2[e2] = __float2bfloat16(w2[(size_t)(tap * 64 + ci) * 128 + n]);
        } else {
            const int e3 = e - 88064;
            const int j = e3 & 7, lane = (e3 >> 3) & 63, nt = (e3 >> 9) & 15, ks = (e3 >> 13) & 3, tap = e3 >> 15;
            const int ci = ks * 32 + ((lane >> 4) << 3) + j;
            const int n  = nt * 16 + (lane & 15);
            wp3[e3] = __float2bfloat16(w3[(size_t)(tap * 128 + ci) * 256 + n]);
        }
    }
}

// ---------- fused conv1+conv2 (256 thr, 4 waves; phase-1 kh-interleaved, mt-split) ----------
// Phase 1, per mtile: one kh loop; B[kh] loaded once, reused by 3 rows (3 A-loads, 12 MFMA
//   per step; live acc = 3x4 f32x4 = 48 VGPR -> no spill at (256,3)). Rows written to LDS
//   in conv2's swizzled A-layout: byte = px*128 + ((jg ^ ((px>>1)&7))*16 + (n&7)*2), jg=n>>3.
//   px128 / row128 zeroed after. Phase 2: 18-slice conv2 K-loop (4 mt x 2 nt / wave).
__global__ __launch_bounds__(256, 3) void k_conv12(const __hip_bfloat16* __restrict__ pv,
                                                   const __hip_bfloat16* __restrict__ w1p,
                                                   const float* __restrict__ b1,
                                                   const __hip_bfloat16* __restrict__ w2p,
                                                   const float* __restrict__ b2,
                                                   __hip_bfloat16* __restrict__ c2p)
{
    __shared__ __align__(16) char lc1[3 * 16512];    // 49,536 B: 3 c1 rows [129px][128B]

    const int xcd = blockIdx.x & 7;
    const int sub = blockIdx.x >> 3;       // 0..383
    const int bt  = xcd * 6 + sub / 64;
    const int oy2 = sub % 64;
    const int tid = threadIdx.x;
    const int w   = tid >> 6;
    const int l   = tid & 63;
    const int li  = l & 15, lh = l >> 4;

    const short* pvS = (const short*)pv;
    const short* w1S = (const short*)w1p;

    // ---- phase 1: 3 conv1 rows, kh-interleaved across rows, split by mtile ----
    const int r0  = oy2 * 2;
    const int ox0 = w * 32;
#pragma unroll
    for (int mt = 0; mt < 2; ++mt) {
        f32x4 acc1[3][4];
#pragma unroll
        for (int row = 0; row < 3; ++row)
#pragma unroll
            for (int n = 0; n < 4; ++n) acc1[row][n] = (f32x4){0.f, 0.f, 0.f, 0.f};

#pragma unroll
        for (int kh = 0; kh < 7; ++kh) {
            bf16x8 bw[4];
#pragma unroll
            for (int nt = 0; nt < 4; ++nt)
                bw[nt] = *reinterpret_cast<const bf16x8*>(w1S + ((size_t)(kh * 4 + nt) * 64 + l) * 8);
#pragma unroll
            for (int row = 0; row < 3; ++row) {
                const int r   = r0 + row;
                const int rcl = (r < 128) ? r : 127;   // clamp (row 128 overwritten with zeros)
                bf16x8 a = *reinterpret_cast<const bf16x8*>(
                    pvS + (size_t)(bt * 261 + rcl * 2 + kh) * 1056 + 8 * (ox0 + mt * 16 + li + lh));
#pragma unroll
                for (int nt = 0; nt < 4; ++nt)
                    acc1[row][nt] = __builtin_amdgcn_mfma_f32_16x16x32_bf16(
                        a, bw[nt], acc1[row][nt], 0, 0, 0);
            }
        }

        // epilogue for this mtile: acc -> LDS (swizzled)
#pragma unroll
        for (int row = 0; row < 3; ++row) {
            if (r0 + row < 128) {          // block-uniform
                char* rowbuf = lc1 + row * 16512;
#pragma unroll
                for (int nt = 0; nt < 4; ++nt) {
                    const int n = nt * 16 + li;
                    const float bias = b1[n];
                    const int jg = nt * 2 + (li >> 3);
#pragma unroll
                    for (int r4 = 0; r4 < 4; ++r4) {
                        const int px = ox0 + mt * 16 + lh * 4 + r4;
                        const float v = fmaxf(acc1[row][nt][r4] * (1.f / 255.f) + bias, 0.f);
                        *reinterpret_cast<unsigned short*>(
                            rowbuf + px * 128 + ((jg ^ ((px >> 1) & 7)) * 16 + (li & 7) * 2)) = bfr(v);
                    }
                }
            }
        }
    }

    // pad handling: px 128 of live rows; full zero row when r==128 (only oy2==63)
#pragma unroll
    for (int row = 0; row < 3; ++row) {
        char* rowbuf = lc1 + row * 16512;
        if (r0 + row < 128) {
            if (tid < 8)                   // zero pad px 128 (swizzle identity)
                *reinterpret_cast<uint4*>(rowbuf + 128 * 128 + tid * 16) = (uint4){0u, 0u, 0u, 0u};
        } else {
#pragma unroll
            for (int it = 0; it < 5; ++it) {
                const int g = it * 256 + tid;
                if (g < 1032)
                    *reinterpret_cast<uint4*>(rowbuf + (size_t)g * 16) = (uint4){0u, 0u, 0u, 0u};
            }
        }
    }
    __syncthreads();                       // only barrier in the kernel

    // ---- phase 2: conv2 K-loop (A from LDS, B from global L2) ----
    const int ntb = w * 2;
    f32x4 acc[4][2];
#pragma unroll
    for (int i = 0; i < 4; ++i) {
        acc[i][0] = (f32x4){0.f, 0.f, 0.f, 0.f};
        acc[i][1] = (f32x4){0.f, 0.f, 0.f, 0.f};
    }

    const char* wB = (const char*)w2p;
#pragma unroll
    for (int s = 0; s < 18; ++s) {
        const int tap = s >> 1, ks = s & 1;
        const int kh = tap / 3, kw = tap % 3;

        bf16x8 bf[2];
#pragma unroll
        for (int j = 0; j < 2; ++j)
            bf[j] = *reinterpret_cast<const bf16x8*>(wB + ((size_t)s * 8 + ntb + j) * 1024 + l * 16);

        const char* Ar = lc1 + kh * 16512;
        bf16x8 af[4];
#pragma unroll
        for (int i = 0; i < 4; ++i) {
            const int ix  = (i * 16 + li) * 2 + kw;
            const int off = ((ks * 4 + lh) ^ ((ix >> 1) & 7)) * 16;
            af[i] = *reinterpret_cast<const bf16x8*>(Ar + (size_t)ix * 128 + off);
        }

#pragma unroll
        for (int i = 0; i < 4; ++i)
#pragma unroll
            for (int j = 0; j < 2; ++j)
                acc[i][j] = __builtin_amdgcn_mfma_f32_16x16x32_bf16(af[i], bf[j], acc[i][j], 0, 0, 0);
    }

    __hip_bfloat16* ob = c2p + (size_t)(bt * 65 + oy2) * 65 * 128;
#pragma unroll
    for (int i = 0; i < 4; ++i) {
        const int ox = i * 16 + lh * 4;
#pragma unroll
        for (int j = 0; j < 2; ++j) {
            const int n = (ntb + j) * 16 + li;
            const float bv = b2[n];
#pragma unroll
            for (int r4 = 0; r4 < 4; ++r4) {
                const float v = fmaxf(acc[i][j][r4] + bv, 0.f);
                ob[(size_t)(ox + r4) * 128 + n] = __float2bfloat16(v);
            }
        }
    }
}

// ---------- row-resident conv3 (barrier-free K-loop, dup-minimized wave split) ----------
template<int CIN, int COUT, int OW, int IW, int ORS, int NTHR, int WMT, int WNT, int MINW>
__global__ __launch_bounds__(NTHR, MINW) void k_convr(const __hip_bfloat16* __restrict__ in,
                                                      const __hip_bfloat16* __restrict__ wp,
                                                      const float* __restrict__ bias,
                                                      __hip_bfloat16* __restrict__ out)
{
    constexpr int KSN  = CIN / 32;
    constexpr int NSL  = 9 * KSN;
    constexpr int NTT  = COUT / 16;
    constexpr int GPX  = CIN / 8;          // 16B granules per pixel
    constexpr int ROWG = IW * GPX;         // granules per input row
    constexpr int RST  = ROWG * 16;        // LDS row stride (bytes)
    constexpr int TOT  = 3 * ROWG;
    constexpr int SIT  = (TOT + NTHR - 1) / NTHR;

    __shared__ char lbuf[3 * RST];

    const int bid = blockIdx.x;
    const int xcd = bid & 7;
    const int sub = bid >> 3;
    const int bt  = xcd * 6 + sub / OW;
    const int oy  = sub % OW;

    const int tid = threadIdx.x;
    const int w   = tid >> 6;
    const int l   = tid & 63;
    const int li  = l & 15, lh = l >> 4;
    const int ntb = w * WNT;

    const short* inS = (const short*)in;
    const size_t rb = (size_t)(bt * IW + oy * 2) * IW * CIN;
#pragma unroll
    for (int it = 0; it < SIT; ++it) {
        const int g = it * NTHR + tid;
        if (g < TOT) {
            const int r  = g / ROWG;
            const int rm = g - r * ROWG;
            const int px = rm / GPX;
            const int j  = rm - px * GPX;
            const int q  = j ^ ((px >> 1) & 7);
            __builtin_amdgcn_global_load_lds(
                (gv_t*)(inS + rb + (size_t)r * IW * CIN + px * CIN + q * 8),
                (sv_t*)(lbuf + (size_t)g * 16), 16, 0, 0);
        }
    }
    __syncthreads();

    f32x4 acc[WMT][WNT];
#pragma unroll
    for (int i = 0; i < WMT; ++i)
#pragma unroll
        for (int j = 0; j < WNT; ++j) acc[i][j] = (f32x4){0.f, 0.f, 0.f, 0.f};

    const char* wB = (const char*)wp;

#pragma unroll
    for (int s = 0; s < NSL; ++s) {
        const int tap = s / KSN, ks = s % KSN;
        const int kh = tap / 3, kw = tap % 3;

        bf16x8 bf[WNT];
#pragma unroll
        for (int j = 0; j < WNT; ++j)
            bf[j] = *reinterpret_cast<const bf16x8*>(wB + ((size_t)s * NTT + ntb + j) * 1024 + l * 16);

        const char* Ar = lbuf + kh * RST;
        bf16x8 af[WMT];
#pragma unroll
        for (int i = 0; i < WMT; ++i) {
            const int ix  = (i * 16 + li) * 2 + kw;
            const int off = ((ks * 4 + lh) ^ ((ix >> 1) & 7)) * 16;
            af[i] = *reinterpret_cast<const bf16x8*>(Ar + (size_t)ix * (CIN * 2) + off);
        }

#pragma unroll
        for (int i = 0; i < WMT; ++i)
#pragma unroll
            for (int j = 0; j < WNT; ++j)
                acc[i][j] = __builtin_amdgcn_mfma_f32_16x16x32_bf16(af[i], bf[j], acc[i][j], 0, 0, 0);
    }

    __hip_bfloat16* ob = out + (size_t)(bt * ORS + oy) * ORS * COUT;
#pragma unroll
    for (int i = 0; i < WMT; ++i) {
        const int ox = i * 16 + lh * 4;
#pragma unroll
        for (int j = 0; j < WNT; ++j) {
            const int n = (ntb + j) * 16 + li;
            const float bv = bias[n];
#pragma unroll
            for (int r = 0; r < 4; ++r) {
                const float v = fmaxf(acc[i][j][r] + bv, 0.f);
                ob[(size_t)(ox + r) * COUT + n] = __float2bfloat16(v);
            }
        }
    }
}

// ---------- bilinear query sampling -> q bf16 [1024,256] ----------
__global__ __launch_bounds__(256) void k_sample(const float* __restrict__ qp,
                                                const __hip_bfloat16* __restrict__ feat,
                                                __hip_bfloat16* __restrict__ q)
{
    const int bn = blockIdx.x;
    const int b  = bn >> 9;
    const float t3 = qp[bn * 3 + 0];
    const float yv = qp[bn * 3 + 1] * 31.f;
    const float xv = qp[bn * 3 + 2] * 31.f;
    int t = (int)(t3 * 23.f);
    t = min(max(t, 0), 23);
    int y0 = (int)floorf(yv); y0 = min(max(y0, 0), 31);
    const int y1 = min(y0 + 1, 31);
    int x0 = (int)floorf(xv); x0 = min(max(x0, 0), 31);
    const int x1 = min(x0 + 1, 31);
    const float wy1 = yv - (float)y0, wy0 = 1.f - wy1;
    const float wx1 = xv - (float)x0, wx0 = 1.f - wx1;

    const int c = threadIdx.x;
    const __hip_bfloat16* fb = feat + ((size_t)(b * 24 + t) * 1024) * 256;
    const float f00 = __bfloat162float(fb[(size_t)(y0 * 32 + x0) * 256 + c]);
    const float f01 = __bfloat162float(fb[(size_t)(y0 * 32 + x1) * 256 + c]);
    const float f10 = __bfloat162float(fb[(size_t)(y1 * 32 + x0) * 256 + c]);
    const float f11 = __bfloat162float(fb[(size_t)(y1 * 32 + x1) * 256 + c]);
    const float v = (f00 * wx0 + f01 * wx1) * wy0 + (f10 * wx0 + f11 * wx1) * wy1;
    q[(size_t)bn * 256 + c] = __float2bfloat16(v);
}

// ---------- correlation: LDS-staged MFMA + online softmax (128 positions / block) ----------
__global__ __launch_bounds__(256, 2) void k_corrm(const __hip_bfloat16* __restrict__ qb,
                                                  const __hip_bfloat16* __restrict__ featb,
                                                  float* __restrict__ pbuf)
{
    __shared__ short lbuf[2][8192];          // 2 x 16KB

    const int bid = blockIdx.x;
    const int xcd = bid & 7;
    const int sub = bid >> 3;
    const int grp = sub >> 5;
    const int prt = sub & 31;
    const int img = xcd * 6 + grp;
    const int bq  = img / 24, t = img % 24;
    const int nc  = prt & 3, ps = prt >> 2;

    const int tid = threadIdx.x;
    const int w   = tid >> 6;
    const int l   = tid & 63;
    const int li  = l & 15, lh = l >> 4;

    const short* qS = (const short*)qb;
    const short* fS = (const short*)featb + (size_t)img * 1024 * 256;
    const char*  tile0 = (const char*)(fS + (size_t)(ps * 128) * 256);

    const int q0 = nc * 128 + w * 32;
    bf16x8 aq[2][8];
#pragma unroll
    for (int mt = 0; mt < 2; ++mt)
#pragma unroll
        for (int ks = 0; ks < 8; ++ks)
            aq[mt][ks] = *reinterpret_cast<const bf16x8*>(
                qS + ((size_t)(bq * 512 + q0 + mt * 16 + li)) * 256 + ks * 32 + lh * 8);

    float m[2][4], s[2][4], sx[2][4], sy[2][4], dmx[2][4];
#pragma unroll
    for (int mt = 0; mt < 2; ++mt)
#pragma unroll
        for (int r = 0; r < 4; ++r) {
            m[mt][r] = -1e30f; s[mt][r] = 0.f; sx[mt][r] = 0.f; sy[mt][r] = 0.f; dmx[mt][r] = -1e30f;
        }

    bf16x8 stg[4];
#pragma unroll
    for (int i = 0; i < 4; ++i) {
        const int g = i * 256 + tid;
        const int pos = g >> 5, kb = (g & 31) * 16;
        stg[i] = *reinterpret_cast<const bf16x8*>(tile0 + (size_t)pos * 512 + kb);
    }
#pragma unroll
    for (int i = 0; i < 4; ++i) {
        const int g = i * 256 + tid;
        const int pos = g >> 5, kb = (g & 31) * 16;
        *reinterpret_cast<bf16x8*>((char*)&lbuf[0][0] + pos * 512 + (kb ^ ((pos & 7) << 4))) = stg[i];
    }
    __syncthreads();

#pragma unroll
    for (int st = 0; st < 4; ++st) {
        const int cur = st & 1;

        if (st < 3) {
            const char* tn = tile0 + (size_t)((st + 1) * 32) * 512;
#pragma unroll
            for (int i = 0; i < 4; ++i) {
                const int g = i * 256 + tid;
                const int pos = g >> 5, kb = (g & 31) * 16;
                stg[i] = *reinterpret_cast<const bf16x8*>(tn + (size_t)pos * 512 + kb);
            }
        }

        f32x4 acc[2][2];
#pragma unroll
        for (int mt = 0; mt < 2; ++mt)
#pragma unroll
            for (int pt = 0; pt < 2; ++pt) acc[mt][pt] = (f32x4){0.f, 0.f, 0.f, 0.f};

#pragma unroll
        for (int pt = 0; pt < 2; ++pt) {
            const int p = pt * 16 + li;
#pragma unroll
            for (int ks = 0; ks < 8; ++ks) {
                const int k = ks * 32 + lh * 8;
                bf16x8 bv = *reinterpret_cast<const bf16x8*>(&lbuf[cur][p * 256 + (k ^ ((p & 7) << 3))]);
                acc[0][pt] = __builtin_amdgcn_mfma_f32_16x16x32_bf16(aq[0][ks], bv, acc[0][pt], 0, 0, 0);
                acc[1][pt] = __builtin_amdgcn_mfma_f32_16x16x32_bf16(aq[1][ks], bv, acc[1][pt], 0, 0, 0);
            }
        }

        const float py = (float)(ps * 4 + st);
#pragma unroll
        for (int mt = 0; mt < 2; ++mt)
#pragma unroll
            for (int r = 0; r < 4; ++r) {
                const float v0 = acc[mt][0][r], v1 = acc[mt][1][r];
                float mx = fmaxf(v0, v1);
                mx = fmaxf(mx, __shfl_xor(mx, 1));
                mx = fmaxf(mx, __shfl_xor(mx, 2));
                mx = fmaxf(mx, __shfl_xor(mx, 4));
                mx = fmaxf(mx, __shfl_xor(mx, 8));
                dmx[mt][r] = fmaxf(dmx[mt][r], mx);
                const float mn = fmaxf(m[mt][r], mx * 0.625f);
                const float sc = __expf(m[mt][r] - mn);
                const float e0 = __expf(v0 * 0.625f - mn);
                const float e1 = __expf(v1 * 0.625f - mn);
                const float es = e0 + e1;
                s[mt][r]  = s[mt][r]  * sc + es;
                sx[mt][r] = sx[mt][r] * sc + es * (float)li + 16.f * e1;
                sy[mt][r] = sy[mt][r] * sc + es * py;
                m[mt][r] = mn;
            }

        if (st < 3) {
#pragma unroll
            for (int i = 0; i < 4; ++i) {
                const int g = i * 256 + tid;
                const int pos = g >> 5, kb = (g & 31) * 16;
                *reinterpret_cast<bf16x8*>((char*)&lbuf[cur ^ 1][0] + pos * 512 + (kb ^ ((pos & 7) << 4))) = stg[i];
            }
            __syncthreads();
        }
    }

#pragma unroll
    for (int mt = 0; mt < 2; ++mt)
#pragma unroll
        for (int r = 0; r < 4; ++r) {
#pragma unroll
            for (int off = 1; off < 16; off <<= 1) {
                s[mt][r]  += __shfl_xor(s[mt][r],  off);
                sx[mt][r] += __shfl_xor(sx[mt][r], off);
                sy[mt][r] += __shfl_xor(sy[mt][r], off);
            }
        }

    if (li == 0) {
#pragma unroll
        for (int mt = 0; mt < 2; ++mt)
#pragma unroll
            for (int r = 0; r < 4; ++r) {
                const int n = q0 + mt * 16 + lh * 4 + r;
                const int bnt = (bq * 512 + n) * 24 + t;
                const int pi = ps * 24576 + bnt;
                pbuf[pi]                = m[mt][r];
                pbuf[196608 + pi]       = s[mt][r];
                pbuf[393216 + pi]       = sx[mt][r];
                pbuf[589824 + pi]       = sy[mt][r];
                pbuf[786432 + pi]       = dmx[mt][r];
            }
    }
}

// ---------- merge 8 position-chunk partials -> outputs ----------
__global__ __launch_bounds__(256) void k_merge(const float* __restrict__ pbuf,
                                               float* __restrict__ outp)
{
    const int i = blockIdx.x * 256 + threadIdx.x;
    float M = -1e30f, D = -1e30f;
#pragma unroll
    for (int ps = 0; ps < 8; ++ps) {
        M = fmaxf(M, pbuf[ps * 24576 + i]);
        D = fmaxf(D, pbuf[786432 + ps * 24576 + i]);
    }
    float s = 0.f, sx = 0.f, sy = 0.f;
#pragma unroll
    for (int ps = 0; ps < 8; ++ps) {
        const int pi = ps * 24576 + i;
        const float wgt = __expf(pbuf[pi] - M);
        s  += pbuf[196608 + pi] * wgt;
        sx += pbuf[393216 + pi] * wgt;
        sy += pbuf[589824 + pi] * wgt;
    }
    const float inv = 8.f / s;
    outp[i * 2 + 0] = sx * inv;
    outp[i * 2 + 1] = sy * inv;
    outp[49152 + i] = 1.f / (1.f + __expf(D * 0.0625f));
}

extern "C" void kernel_launch(void* const* d_in, const int* in_sizes, int n_in,
                              void* d_out, int out_size, void* d_ws, size_t ws_size,
                              hipStream_t stream)
{
    const float* video = (const float*)d_in[0];
    const float* qp    = (const float*)d_in[1];
    const float* w1    = (const float*)d_in[2];
    const float* b1    = (const float*)d_in[3];
    const float* w2    = (const float*)d_in[4];
    const float* b2    = (const float*)d_in[5];
    const float* w3    = (const float*)d_in[6];
    const float* b3    = (const float*)d_in[7];
    float* out = (float*)d_out;

    char* wsb = (char*)d_ws;
    __hip_bfloat16* c2p   = (__hip_bfloat16*)(wsb);                    //  51,916,800 B
    __hip_bfloat16* pv    = (__hip_bfloat16*)(wsb + 51916800ull);      //  26,459,136 B (dead after conv12)
    __hip_bfloat16* featb = (__hip_bfloat16*)(wsb + 51916800ull);      //  25,165,824 B
    __hip_bfloat16* qbuf  = (__hip_bfloat16*)(wsb + 78375936ull);      //     524,288 B
    __hip_bfloat16* w1p   = (__hip_bfloat16*)(wsb + 78900224ull);      //      28,672 B
    __hip_bfloat16* w2p   = (__hip_bfloat16*)(wsb + 78928896ull);      //     147,456 B
    __hip_bfloat16* w3p   = (__hip_bfloat16*)(wsb + 79076352ull);      //     589,824 B
    float*          pbuf  = (float*)(wsb + 79666176ull);               //   3,932,160 B

    k_prep   <<<dim3(17870), dim3(256), 0, stream>>>(
                  video, w1, w2, w3, pv, (unsigned short*)c2p, w1p, w2p, w3p);
    k_conv12 <<<dim3(3072),  dim3(256), 0, stream>>>(pv, w1p, b1, w2p, b2, c2p);
    k_convr<128, 256, 32, 65, 32, 512, 2, 2, 6><<<dim3(1536), dim3(512), 0, stream>>>(c2p, w3p, b3, featb);
    k_sample <<<dim3(1024),  dim3(256), 0, stream>>>(qp, featb, qbuf);
    k_corrm  <<<dim3(1536),  dim3(256), 0, stream>>>(qbuf, featb, pbuf);
    k_merge  <<<dim3(96),    dim3(256), 0, stream>>>(pbuf, out);
}

// Round 20
// 170.552 us; speedup vs baseline: 1.0988x; 1.0988x over previous
//
#include <hip/hip_runtime.h>
#include <hip/hip_bf16.h>
#include <cstdint>
#include <cstddef>

// Pipeline (all convs MFMA; conv1 FUSED into conv2 -> c1p intermediate eliminated):
//   k_prep:   pad video -> pv[48,261,1056]bf16 | zero pad strips (pv,c2p) | repack w1/w2/w3
//   k_conv12: pv -> (3 conv1 rows in LDS, kh-interleaved across rows; (256,2) so acc stays
//             in registers, no scratch spill) -> c2p, one barrier
//   k_convr<128,256,...>: c2p -> featb[48,32,32,256]bf16 (row-resident, barrier-free K-loop)
//   k_sample: bilinear q[1024,256]bf16
//   k_corrm:  LDS-staged MFMA corr + online softmax over 128-position chunks -> partials
//   k_merge:  combine 8 position-chunk partials -> pred/occl f32
//
// MFMA 16x16x32 bf16 layouts (verified):
//   A: lane l holds row=l&15,   k=(l>>4)*8+j  (bf16x8 contiguous)
//   B: lane l holds col=l&15,   k=(l>>4)*8+j
//   C: lane l holds col=l&15, row=(l>>4)*4+reg (f32x4)

typedef __attribute__((ext_vector_type(8))) short bf16x8;
typedef __attribute__((ext_vector_type(4))) float f32x4;

typedef const __attribute__((address_space(1))) void gv_t;   // global
typedef __attribute__((address_space(3))) void sv_t;         // LDS

__device__ __forceinline__ unsigned short bfr(float f) {
    return (unsigned short)(__bfloat16_as_ushort(__float2bfloat16(f)));
}

// ---------- fused prep: pad+cast video | zero pad strips (pv, c2p) | weight repacks ----------
__global__ __launch_bounds__(256) void k_prep(const float* __restrict__ video,
                                              const float* __restrict__ w1,
                                              const float* __restrict__ w2,
                                              const float* __restrict__ w3,
                                              __hip_bfloat16* __restrict__ pv,
                                              unsigned short* __restrict__ c2p,
                                              __hip_bfloat16* __restrict__ wp1,
                                              __hip_bfloat16* __restrict__ wp2,
                                              __hip_bfloat16* __restrict__ wp3)
{
    const int bid = blockIdx.x;
    if (bid < 12288) {
        const int iy = bid & 255;
        const int bt = bid >> 8;
        const int ix = threadIdx.x;
        const float* src = video + ((size_t)(bt * 256 + iy) * 256 + ix) * 3;
        unsigned* dst = (unsigned*)(pv + ((size_t)(bt * 261) + iy + 2) * 1056);
        const float v0 = src[0], v1 = src[1], v2 = src[2];
        const unsigned lo = (unsigned)bfr(v0) | ((unsigned)bfr(v1) << 16);
        const unsigned hi = (unsigned)bfr(v2);
        dst[(2 + ix) * 2 + 0] = lo;
        dst[(2 + ix) * 2 + 1] = hi;
        if (ix < 2)   { dst[ix * 2] = 0u; dst[ix * 2 + 1] = 0u; }
        if (ix >= 250){ dst[(ix + 8) * 2] = 0u; dst[(ix + 8) * 2 + 1] = 0u; }
    } else if (bid < 12288 + 4086) {
        const int i = (bid - 12288) * 256 + threadIdx.x;     // 1,046,016 total
        unsigned short* pvs = (unsigned short*)pv;
        if (i < 253440) {                                    // pv strips
            const int bt = i / 5280, rr = (i % 5280) / 1056, col = i % 1056;
            const int row = (rr < 2) ? rr : rr + 256;
            pvs[(size_t)(bt * 261 + row) * 1056 + col] = 0;
        } else {                                             // c2p strips: 48 x 16512
            const int j = i - 253440, bt = j / 16512, k = j % 16512;
            size_t addr;
            if (k < 8320) { const int px = k >> 7, c = k & 127;
                addr = ((size_t)(bt * 65 + 64) * 65 + px) * 128 + c; }
            else { const int k2 = k - 8320, row = k2 >> 7, c = k2 & 127;
                addr = ((size_t)(bt * 65 + row) * 65 + 64) * 128 + c; }
            c2p[addr] = 0;
        }
    } else {
        const int e = (bid - 12288 - 4086) * 256 + threadIdx.x;   // 382,976 total
        if (e < 14336) {
            const int j = e & 7, lane = (e >> 3) & 63, nt = (e >> 9) & 3, kh = e >> 11;
            const int k = ((lane >> 4) << 3) + j;
            const int kw = k >> 2, ci = k & 3;
            const int n = nt * 16 + (lane & 15);
            float v = (ci < 3 && kw < 7) ? w1[(size_t)((kh * 7 + kw) * 3 + ci) * 64 + n] : 0.f;
            wp1[e] = __float2bfloat16(v);
        } else if (e < 88064) {
            const int e2 = e - 14336;
            const int j = e2 & 7, lane = (e2 >> 3) & 63, nt = (e2 >> 9) & 7, ks = (e2 >> 12) & 1, tap = e2 >> 13;
            const int ci = ks * 32 + ((lane >> 4) << 3) + j;
            const int n  = nt * 16 + (lane & 15);
            wp2[e2] = __float2bfloat16(w2[(size_t)(tap * 64 + ci) * 128 + n]);
        } else {
            const int e3 = e - 88064;
            const int j = e3 & 7, lane = (e3 >> 3) & 63, nt = (e3 >> 9) & 15, ks = (e3 >> 13) & 3, tap = e3 >> 15;
            const int ci = ks * 32 + ((lane >> 4) << 3) + j;
            const int n  = nt * 16 + (lane & 15);
            wp3[e3] = __float2bfloat16(w3[(size_t)(tap * 128 + ci) * 256 + n]);
        }
    }
}

// ---------- fused conv1+conv2 (256 thr, 4 waves; phase-1 kh-interleaved across 3 rows) ----------
// Phase 1: one kh loop; B[kh] loaded once, reused by 3 rows x 2 mt (6 independent A-loads,
//   24 MFMA per step; serial depth 7). launch_bounds (256,2): acc1 96 VGPR stays in regs.
//   Rows written to LDS in conv2's swizzled A-layout:
//   byte = px*128 + ((jg ^ ((px>>1)&7))*16 + (n&7)*2), jg=n>>3. px128 / row128 zeroed.
// Phase 2: 18-slice conv2 K-loop; wave = 4 mtiles x 2 ntiles, A from LDS, B=w2p from L2.
__global__ __launch_bounds__(256, 2) void k_conv12(const __hip_bfloat16* __restrict__ pv,
                                                   const __hip_bfloat16* __restrict__ w1p,
                                                   const float* __restrict__ b1,
                                                   const __hip_bfloat16* __restrict__ w2p,
                                                   const float* __restrict__ b2,
                                                   __hip_bfloat16* __restrict__ c2p)
{
    __shared__ __align__(16) char lc1[3 * 16512];    // 49,536 B: 3 c1 rows [129px][128B]

    const int xcd = blockIdx.x & 7;
    const int sub = blockIdx.x >> 3;       // 0..383
    const int bt  = xcd * 6 + sub / 64;
    const int oy2 = sub % 64;
    const int tid = threadIdx.x;
    const int w   = tid >> 6;
    const int l   = tid & 63;
    const int li  = l & 15, lh = l >> 4;

    const short* pvS = (const short*)pv;
    const short* w1S = (const short*)w1p;

    // ---- phase 1: 3 conv1 rows, kh-interleaved ----
    const int r0 = oy2 * 2;
    f32x4 acc1[3][2][4];
#pragma unroll
    for (int row = 0; row < 3; ++row)
#pragma unroll
        for (int m = 0; m < 2; ++m)
#pragma unroll
            for (int n = 0; n < 4; ++n) acc1[row][m][n] = (f32x4){0.f, 0.f, 0.f, 0.f};

    const int ox0 = w * 32;
#pragma unroll
    for (int kh = 0; kh < 7; ++kh) {
        bf16x8 bw[4];
#pragma unroll
        for (int nt = 0; nt < 4; ++nt)
            bw[nt] = *reinterpret_cast<const bf16x8*>(w1S + ((size_t)(kh * 4 + nt) * 64 + l) * 8);
#pragma unroll
        for (int row = 0; row < 3; ++row) {
            const int r   = r0 + row;
            const int rcl = (r < 128) ? r : 127;       // clamp (row 128 overwritten with zeros)
            const short* rbase = pvS + (size_t)(bt * 261 + rcl * 2 + kh) * 1056;
#pragma unroll
            for (int mt = 0; mt < 2; ++mt) {
                bf16x8 a = *reinterpret_cast<const bf16x8*>(
                    rbase + 8 * (ox0 + mt * 16 + li + lh));
#pragma unroll
                for (int nt = 0; nt < 4; ++nt)
                    acc1[row][mt][nt] = __builtin_amdgcn_mfma_f32_16x16x32_bf16(
                        a, bw[nt], acc1[row][mt][nt], 0, 0, 0);
            }
        }
    }

    // epilogue: acc -> LDS (swizzled); pad rows/px zeroed
#pragma unroll
    for (int row = 0; row < 3; ++row) {
        const int r = r0 + row;
        char* rowbuf = lc1 + row * 16512;
        if (r < 128) {                     // block-uniform
#pragma unroll
            for (int mt = 0; mt < 2; ++mt) {
#pragma unroll
                for (int nt = 0; nt < 4; ++nt) {
                    const int n = nt * 16 + li;
                    const float bias = b1[n];
                    const int jg = nt * 2 + (li >> 3);
#pragma unroll
                    for (int r4 = 0; r4 < 4; ++r4) {
                        const int px = ox0 + mt * 16 + lh * 4 + r4;
                        const float v = fmaxf(acc1[row][mt][nt][r4] * (1.f / 255.f) + bias, 0.f);
                        *reinterpret_cast<unsigned short*>(
                            rowbuf + px * 128 + ((jg ^ ((px >> 1) & 7)) * 16 + (li & 7) * 2)) = bfr(v);
                    }
                }
            }
            if (tid < 8)                   // zero pad px 128 (swizzle identity)
                *reinterpret_cast<uint4*>(rowbuf + 128 * 128 + tid * 16) = (uint4){0u, 0u, 0u, 0u};
        } else {                           // r == 128: SAME-pad zero row (only oy2==63)
#pragma unroll
            for (int it = 0; it < 5; ++it) {
                const int g = it * 256 + tid;
                if (g < 1032)
                    *reinterpret_cast<uint4*>(rowbuf + (size_t)g * 16) = (uint4){0u, 0u, 0u, 0u};
            }
        }
    }
    __syncthreads();                       // only barrier in the kernel

    // ---- phase 2: conv2 K-loop (A from LDS, B from global L2) ----
    const int ntb = w * 2;
    f32x4 acc[4][2];
#pragma unroll
    for (int i = 0; i < 4; ++i) {
        acc[i][0] = (f32x4){0.f, 0.f, 0.f, 0.f};
        acc[i][1] = (f32x4){0.f, 0.f, 0.f, 0.f};
    }

    const char* wB = (const char*)w2p;
#pragma unroll
    for (int s = 0; s < 18; ++s) {
        const int tap = s >> 1, ks = s & 1;
        const int kh = tap / 3, kw = tap % 3;

        bf16x8 bf[2];
#pragma unroll
        for (int j = 0; j < 2; ++j)
            bf[j] = *reinterpret_cast<const bf16x8*>(wB + ((size_t)s * 8 + ntb + j) * 1024 + l * 16);

        const char* Ar = lc1 + kh * 16512;
        bf16x8 af[4];
#pragma unroll
        for (int i = 0; i < 4; ++i) {
            const int ix  = (i * 16 + li) * 2 + kw;
            const int off = ((ks * 4 + lh) ^ ((ix >> 1) & 7)) * 16;
            af[i] = *reinterpret_cast<const bf16x8*>(Ar + (size_t)ix * 128 + off);
        }

#pragma unroll
        for (int i = 0; i < 4; ++i)
#pragma unroll
            for (int j = 0; j < 2; ++j)
                acc[i][j] = __builtin_amdgcn_mfma_f32_16x16x32_bf16(af[i], bf[j], acc[i][j], 0, 0, 0);
    }

    __hip_bfloat16* ob = c2p + (size_t)(bt * 65 + oy2) * 65 * 128;
#pragma unroll
    for (int i = 0; i < 4; ++i) {
        const int ox = i * 16 + lh * 4;
#pragma unroll
        for (int j = 0; j < 2; ++j) {
            const int n = (ntb + j) * 16 + li;
            const float bv = b2[n];
#pragma unroll
            for (int r4 = 0; r4 < 4; ++r4) {
                const float v = fmaxf(acc[i][j][r4] + bv, 0.f);
                ob[(size_t)(ox + r4) * 128 + n] = __float2bfloat16(v);
            }
        }
    }
}

// ---------- row-resident conv3 (barrier-free K-loop, dup-minimized wave split) ----------
template<int CIN, int COUT, int OW, int IW, int ORS, int NTHR, int WMT, int WNT, int MINW>
__global__ __launch_bounds__(NTHR, MINW) void k_convr(const __hip_bfloat16* __restrict__ in,
                                                      const __hip_bfloat16* __restrict__ wp,
                                                      const float* __restrict__ bias,
                                                      __hip_bfloat16* __restrict__ out)
{
    constexpr int KSN  = CIN / 32;
    constexpr int NSL  = 9 * KSN;
    constexpr int NTT  = COUT / 16;
    constexpr int GPX  = CIN / 8;          // 16B granules per pixel
    constexpr int ROWG = IW * GPX;         // granules per input row
    constexpr int RST  = ROWG * 16;        // LDS row stride (bytes)
    constexpr int TOT  = 3 * ROWG;
    constexpr int SIT  = (TOT + NTHR - 1) / NTHR;

    __shared__ char lbuf[3 * RST];

    const int bid = blockIdx.x;
    const int xcd = bid & 7;
    const int sub = bid >> 3;
    const int bt  = xcd * 6 + sub / OW;
    const int oy  = sub % OW;

    const int tid = threadIdx.x;
    const int w   = tid >> 6;
    const int l   = tid & 63;
    const int li  = l & 15, lh = l >> 4;
    const int ntb = w * WNT;

    const short* inS = (const short*)in;
    const size_t rb = (size_t)(bt * IW + oy * 2) * IW * CIN;
#pragma unroll
    for (int it = 0; it < SIT; ++it) {
        const int g = it * NTHR + tid;
        if (g < TOT) {
            const int r  = g / ROWG;
            const int rm = g - r * ROWG;
            const int px = rm / GPX;
            const int j  = rm - px * GPX;
            const int q  = j ^ ((px >> 1) & 7);
            __builtin_amdgcn_global_load_lds(
                (gv_t*)(inS + rb + (size_t)r * IW * CIN + px * CIN + q * 8),
                (sv_t*)(lbuf + (size_t)g * 16), 16, 0, 0);
        }
    }
    __syncthreads();

    f32x4 acc[WMT][WNT];
#pragma unroll
    for (int i = 0; i < WMT; ++i)
#pragma unroll
        for (int j = 0; j < WNT; ++j) acc[i][j] = (f32x4){0.f, 0.f, 0.f, 0.f};

    const char* wB = (const char*)wp;

#pragma unroll
    for (int s = 0; s < NSL; ++s) {
        const int tap = s / KSN, ks = s % KSN;
        const int kh = tap / 3, kw = tap % 3;

        bf16x8 bf[WNT];
#pragma unroll
        for (int j = 0; j < WNT; ++j)
            bf[j] = *reinterpret_cast<const bf16x8*>(wB + ((size_t)s * NTT + ntb + j) * 1024 + l * 16);

        const char* Ar = lbuf + kh * RST;
        bf16x8 af[WMT];
#pragma unroll
        for (int i = 0; i < WMT; ++i) {
            const int ix  = (i * 16 + li) * 2 + kw;
            const int off = ((ks * 4 + lh) ^ ((ix >> 1) & 7)) * 16;
            af[i] = *reinterpret_cast<const bf16x8*>(Ar + (size_t)ix * (CIN * 2) + off);
        }

#pragma unroll
        for (int i = 0; i < WMT; ++i)
#pragma unroll
            for (int j = 0; j < WNT; ++j)
                acc[i][j] = __builtin_amdgcn_mfma_f32_16x16x32_bf16(af[i], bf[j], acc[i][j], 0, 0, 0);
    }

    __hip_bfloat16* ob = out + (size_t)(bt * ORS + oy) * ORS * COUT;
#pragma unroll
    for (int i = 0; i < WMT; ++i) {
        const int ox = i * 16 + lh * 4;
#pragma unroll
        for (int j = 0; j < WNT; ++j) {
            const int n = (ntb + j) * 16 + li;
            const float bv = bias[n];
#pragma unroll
            for (int r = 0; r < 4; ++r) {
                const float v = fmaxf(acc[i][j][r] + bv, 0.f);
                ob[(size_t)(ox + r) * COUT + n] = __float2bfloat16(v);
            }
        }
    }
}

// ---------- bilinear query sampling -> q bf16 [1024,256] ----------
__global__ __launch_bounds__(256) void k_sample(const float* __restrict__ qp,
                                                const __hip_bfloat16* __restrict__ feat,
                                                __hip_bfloat16* __restrict__ q)
{
    const int bn = blockIdx.x;
    const int b  = bn >> 9;
    const float t3 = qp[bn * 3 + 0];
    const float yv = qp[bn * 3 + 1] * 31.f;
    const float xv = qp[bn * 3 + 2] * 31.f;
    int t = (int)(t3 * 23.f);
    t = min(max(t, 0), 23);
    int y0 = (int)floorf(yv); y0 = min(max(y0, 0), 31);
    const int y1 = min(y0 + 1, 31);
    int x0 = (int)floorf(xv); x0 = min(max(x0, 0), 31);
    const int x1 = min(x0 + 1, 31);
    const float wy1 = yv - (float)y0, wy0 = 1.f - wy1;
    const float wx1 = xv - (float)x0, wx0 = 1.f - wx1;

    const int c = threadIdx.x;
    const __hip_bfloat16* fb = feat + ((size_t)(b * 24 + t) * 1024) * 256;
    const float f00 = __bfloat162float(fb[(size_t)(y0 * 32 + x0) * 256 + c]);
    const float f01 = __bfloat162float(fb[(size_t)(y0 * 32 + x1) * 256 + c]);
    const float f10 = __bfloat162float(fb[(size_t)(y1 * 32 + x0) * 256 + c]);
    const float f11 = __bfloat162float(fb[(size_t)(y1 * 32 + x1) * 256 + c]);
    const float v = (f00 * wx0 + f01 * wx1) * wy0 + (f10 * wx0 + f11 * wx1) * wy1;
    q[(size_t)bn * 256 + c] = __float2bfloat16(v);
}

// ---------- correlation: LDS-staged MFMA + online softmax (128 positions / block) ----------
__global__ __launch_bounds__(256, 2) void k_corrm(const __hip_bfloat16* __restrict__ qb,
                                                  const __hip_bfloat16* __restrict__ featb,
                                                  float* __restrict__ pbuf)
{
    __shared__ short lbuf[2][8192];          // 2 x 16KB

    const int bid = blockIdx.x;
    const int xcd = bid & 7;
    const int sub = bid >> 3;
    const int grp = sub >> 5;
    const int prt = sub & 31;
    const int img = xcd * 6 + grp;
    const int bq  = img / 24, t = img % 24;
    const int nc  = prt & 3, ps = prt >> 2;

    const int tid = threadIdx.x;
    const int w   = tid >> 6;
    const int l   = tid & 63;
    const int li  = l & 15, lh = l >> 4;

    const short* qS = (const short*)qb;
    const short* fS = (const short*)featb + (size_t)img * 1024 * 256;
    const char*  tile0 = (const char*)(fS + (size_t)(ps * 128) * 256);

    const int q0 = nc * 128 + w * 32;
    bf16x8 aq[2][8];
#pragma unroll
    for (int mt = 0; mt < 2; ++mt)
#pragma unroll
        for (int ks = 0; ks < 8; ++ks)
            aq[mt][ks] = *reinterpret_cast<const bf16x8*>(
                qS + ((size_t)(bq * 512 + q0 + mt * 16 + li)) * 256 + ks * 32 + lh * 8);

    float m[2][4], s[2][4], sx[2][4], sy[2][4], dmx[2][4];
#pragma unroll
    for (int mt = 0; mt < 2; ++mt)
#pragma unroll
        for (int r = 0; r < 4; ++r) {
            m[mt][r] = -1e30f; s[mt][r] = 0.f; sx[mt][r] = 0.f; sy[mt][r] = 0.f; dmx[mt][r] = -1e30f;
        }

    bf16x8 stg[4];
#pragma unroll
    for (int i = 0; i < 4; ++i) {
        const int g = i * 256 + tid;
        const int pos = g >> 5, kb = (g & 31) * 16;
        stg[i] = *reinterpret_cast<const bf16x8*>(tile0 + (size_t)pos * 512 + kb);
    }
#pragma unroll
    for (int i = 0; i < 4; ++i) {
        const int g = i * 256 + tid;
        const int pos = g >> 5, kb = (g & 31) * 16;
        *reinterpret_cast<bf16x8*>((char*)&lbuf[0][0] + pos * 512 + (kb ^ ((pos & 7) << 4))) = stg[i];
    }
    __syncthreads();

#pragma unroll
    for (int st = 0; st < 4; ++st) {
        const int cur = st & 1;

        if (st < 3) {
            const char* tn = tile0 + (size_t)((st + 1) * 32) * 512;
#pragma unroll
            for (int i = 0; i < 4; ++i) {
                const int g = i * 256 + tid;
                const int pos = g >> 5, kb = (g & 31) * 16;
                stg[i] = *reinterpret_cast<const bf16x8*>(tn + (size_t)pos * 512 + kb);
            }
        }

        f32x4 acc[2][2];
#pragma unroll
        for (int mt = 0; mt < 2; ++mt)
#pragma unroll
            for (int pt = 0; pt < 2; ++pt) acc[mt][pt] = (f32x4){0.f, 0.f, 0.f, 0.f};

#pragma unroll
        for (int pt = 0; pt < 2; ++pt) {
            const int p = pt * 16 + li;
#pragma unroll
            for (int ks = 0; ks < 8; ++ks) {
                const int k = ks * 32 + lh * 8;
                bf16x8 bv = *reinterpret_cast<const bf16x8*>(&lbuf[cur][p * 256 + (k ^ ((p & 7) << 3))]);
                acc[0][pt] = __builtin_amdgcn_mfma_f32_16x16x32_bf16(aq[0][ks], bv, acc[0][pt], 0, 0, 0);
                acc[1][pt] = __builtin_amdgcn_mfma_f32_16x16x32_bf16(aq[1][ks], bv, acc[1][pt], 0, 0, 0);
            }
        }

        const float py = (float)(ps * 4 + st);
#pragma unroll
        for (int mt = 0; mt < 2; ++mt)
#pragma unroll
            for (int r = 0; r < 4; ++r) {
                const float v0 = acc[mt][0][r], v1 = acc[mt][1][r];
                float mx = fmaxf(v0, v1);
                mx = fmaxf(mx, __shfl_xor(mx, 1));
                mx = fmaxf(mx, __shfl_xor(mx, 2));
                mx = fmaxf(mx, __shfl_xor(mx, 4));
                mx = fmaxf(mx, __shfl_xor(mx, 8));
                dmx[mt][r] = fmaxf(dmx[mt][r], mx);
                const float mn = fmaxf(m[mt][r], mx * 0.625f);
                const float sc = __expf(m[mt][r] - mn);
                const float e0 = __expf(v0 * 0.625f - mn);
                const float e1 = __expf(v1 * 0.625f - mn);
                const float es = e0 + e1;
                s[mt][r]  = s[mt][r]  * sc + es;
                sx[mt][r] = sx[mt][r] * sc + es * (float)li + 16.f * e1;
                sy[mt][r] = sy[mt][r] * sc + es * py;
                m[mt][r] = mn;
            }

        if (st < 3) {
#pragma unroll
            for (int i = 0; i < 4; ++i) {
                const int g = i * 256 + tid;
                const int pos = g >> 5, kb = (g & 31) * 16;
                *reinterpret_cast<bf16x8*>((char*)&lbuf[cur ^ 1][0] + pos * 512 + (kb ^ ((pos & 7) << 4))) = stg[i];
            }
            __syncthreads();
        }
    }

#pragma unroll
    for (int mt = 0; mt < 2; ++mt)
#pragma unroll
        for (int r = 0; r < 4; ++r) {
#pragma unroll
            for (int off = 1; off < 16; off <<= 1) {
                s[mt][r]  += __shfl_xor(s[mt][r],  off);
                sx[mt][r] += __shfl_xor(sx[mt][r], off);
                sy[mt][r] += __shfl_xor(sy[mt][r], off);
            }
        }

    if (li == 0) {
#pragma unroll
        for (int mt = 0; mt < 2; ++mt)
#pragma unroll
            for (int r = 0; r < 4; ++r) {
                const int n = q0 + mt * 16 + lh * 4 + r;
                const int bnt = (bq * 512 + n) * 24 + t;
                const int pi = ps * 24576 + bnt;
                pbuf[pi]                = m[mt][r];
                pbuf[196608 + pi]       = s[mt][r];
                pbuf[393216 + pi]       = sx[mt][r];
                pbuf[589824 + pi]       = sy[mt][r];
                pbuf[786432 + pi]       = dmx[mt][r];
            }
    }
}

// ---------- merge 8 position-chunk partials -> outputs ----------
__global__ __launch_bounds__(256) void k_merge(const float* __restrict__ pbuf,
                                               float* __restrict__ outp)
{
    const int i = blockIdx.x * 256 + threadIdx.x;
    float M = -1e30f, D = -1e30f;
#pragma unroll
    for (int ps = 0; ps < 8; ++ps) {
        M = fmaxf(M, pbuf[ps * 24576 + i]);
        D = fmaxf(D, pbuf[786432 + ps * 24576 + i]);
    }
    float s = 0.f, sx = 0.f, sy = 0.f;
#pragma unroll
    for (int ps = 0; ps < 8; ++ps) {
        const int pi = ps * 24576 + i;
        const float wgt = __expf(pbuf[pi] - M);
        s  += pbuf[196608 + pi] * wgt;
        sx += pbuf[393216 + pi] * wgt;
        sy += pbuf[589824 + pi] * wgt;
    }
    const float inv = 8.f / s;
    outp[i * 2 + 0] = sx * inv;
    outp[i * 2 + 1] = sy * inv;
    outp[49152 + i] = 1.f / (1.f + __expf(D * 0.0625f));
}

extern "C" void kernel_launch(void* const* d_in, const int* in_sizes, int n_in,
                              void* d_out, int out_size, void* d_ws, size_t ws_size,
                              hipStream_t stream)
{
    const float* video = (const float*)d_in[0];
    const float* qp    = (const float*)d_in[1];
    const float* w1    = (const float*)d_in[2];
    const float* b1    = (const float*)d_in[3];
    const float* w2    = (const float*)d_in[4];
    const float* b2    = (const float*)d_in[5];
    const float* w3    = (const float*)d_in[6];
    const float* b3    = (const float*)d_in[7];
    float* out = (float*)d_out;

    char* wsb = (char*)d_ws;
    __hip_bfloat16* c2p   = (__hip_bfloat16*)(wsb);                    //  51,916,800 B
    __hip_bfloat16* pv    = (__hip_bfloat16*)(wsb + 51916800ull);      //  26,459,136 B (dead after conv12)
    __hip_bfloat16* featb = (__hip_bfloat16*)(wsb + 51916800ull);      //  25,165,824 B
    __hip_bfloat16* qbuf  = (__hip_bfloat16*)(wsb + 78375936ull);      //     524,288 B
    __hip_bfloat16* w1p   = (__hip_bfloat16*)(wsb + 78900224ull);      //      28,672 B
    __hip_bfloat16* w2p   = (__hip_bfloat16*)(wsb + 78928896ull);      //     147,456 B
    __hip_bfloat16* w3p   = (__hip_bfloat16*)(wsb + 79076352ull);      //     589,824 B
    float*          pbuf  = (float*)(wsb + 79666176ull);               //   3,932,160 B

    k_prep   <<<dim3(17870), dim3(256), 0, stream>>>(
                  video, w1, w2, w3, pv, (unsigned short*)c2p, w1p, w2p, w3p);
    k_conv12 <<<dim3(3072),  dim3(256), 0, stream>>>(pv, w1p, b1, w2p, b2, c2p);
    k_convr<128, 256, 32, 65, 32, 512, 2, 2, 6><<<dim3(1536), dim3(512), 0, stream>>>(c2p, w3p, b3, featb);
    k_sample <<<dim3(1024),  dim3(256), 0, stream>>>(qp, featb, qbuf);
    k_corrm  <<<dim3(1536),  dim3(256), 0, stream>>>(qbuf, featb, pbuf);
    k_merge  <<<dim3(96),    dim3(256), 0, stream>>>(pbuf, out);
}

// Round 21
// 169.285 us; speedup vs baseline: 1.1070x; 1.0075x over previous
//
#include <hip/hip_runtime.h>
#include <hip/hip_bf16.h>
#include <cstdint>
#include <cstddef>

// Pipeline (all convs MFMA; conv1 FUSED into conv2 -> c1p intermediate eliminated):
//   k_prep:   pad video -> pv[48,261,1056]bf16 (XCD-ALIGNED with conv12: image bt on XCD bt/6)
//             | zero pad strips (pv,c2p) | repack w1/w2/w3
//   k_conv12: pv -> (3 conv1 rows in LDS, kh-interleaved; (256,2), no spill) -> c2p, one barrier
//   k_convr<128,256,...>: c2p -> featb[48,32,32,256]bf16 (row-resident, barrier-free K-loop)
//   k_sample: bilinear q[1024,256]bf16
//   k_corrm:  LDS-staged MFMA corr + online softmax over 128-position chunks -> partials
//   k_merge:  combine 8 position-chunk partials -> pred/occl f32
//
// MFMA 16x16x32 bf16 layouts (verified):
//   A: lane l holds row=l&15,   k=(l>>4)*8+j  (bf16x8 contiguous)
//   B: lane l holds col=l&15,   k=(l>>4)*8+j
//   C: lane l holds col=l&15, row=(l>>4)*4+reg (f32x4)

typedef __attribute__((ext_vector_type(8))) short bf16x8;
typedef __attribute__((ext_vector_type(4))) float f32x4;

typedef const __attribute__((address_space(1))) void gv_t;   // global
typedef __attribute__((address_space(3))) void sv_t;         // LDS

__device__ __forceinline__ unsigned short bfr(float f) {
    return (unsigned short)(__bfloat16_as_ushort(__float2bfloat16(f)));
}

// ---------- fused prep: pad+cast video | zero pad strips (pv, c2p) | weight repacks ----------
__global__ __launch_bounds__(256) void k_prep(const float* __restrict__ video,
                                              const float* __restrict__ w1,
                                              const float* __restrict__ w2,
                                              const float* __restrict__ w3,
                                              __hip_bfloat16* __restrict__ pv,
                                              unsigned short* __restrict__ c2p,
                                              __hip_bfloat16* __restrict__ wp1,
                                              __hip_bfloat16* __restrict__ wp2,
                                              __hip_bfloat16* __restrict__ wp3)
{
    const int bid = blockIdx.x;
    if (bid < 12288) {
        // XCD-aligned pad: image bt handled by blocks on XCD bt/6 (matches k_conv12's reader)
        const int xcd = bid & 7;
        const int sub = bid >> 3;          // 0..1535
        const int bt  = xcd * 6 + (sub >> 8);
        const int iy  = sub & 255;
        const int ix = threadIdx.x;
        const float* src = video + ((size_t)(bt * 256 + iy) * 256 + ix) * 3;
        unsigned* dst = (unsigned*)(pv + ((size_t)(bt * 261) + iy + 2) * 1056);
        const float v0 = src[0], v1 = src[1], v2 = src[2];
        const unsigned lo = (unsigned)bfr(v0) | ((unsigned)bfr(v1) << 16);
        const unsigned hi = (unsigned)bfr(v2);
        dst[(2 + ix) * 2 + 0] = lo;
        dst[(2 + ix) * 2 + 1] = hi;
        if (ix < 2)   { dst[ix * 2] = 0u; dst[ix * 2 + 1] = 0u; }
        if (ix >= 250){ dst[(ix + 8) * 2] = 0u; dst[(ix + 8) * 2 + 1] = 0u; }
    } else if (bid < 12288 + 4086) {
        const int i = (bid - 12288) * 256 + threadIdx.x;     // 1,046,016 total
        unsigned short* pvs = (unsigned short*)pv;
        if (i < 253440) {                                    // pv strips
            const int bt = i / 5280, rr = (i % 5280) / 1056, col = i % 1056;
            const int row = (rr < 2) ? rr : rr + 256;
            pvs[(size_t)(bt * 261 + row) * 1056 + col] = 0;
        } else {                                             // c2p strips: 48 x 16512
            const int j = i - 253440, bt = j / 16512, k = j % 16512;
            size_t addr;
            if (k < 8320) { const int px = k >> 7, c = k & 127;
                addr = ((size_t)(bt * 65 + 64) * 65 + px) * 128 + c; }
            else { const int k2 = k - 8320, row = k2 >> 7, c = k2 & 127;
                addr = ((size_t)(bt * 65 + row) * 65 + 64) * 128 + c; }
            c2p[addr] = 0;
        }
    } else {
        const int e = (bid - 12288 - 4086) * 256 + threadIdx.x;   // 382,976 total
        if (e < 14336) {
            const int j = e & 7, lane = (e >> 3) & 63, nt = (e >> 9) & 3, kh = e >> 11;
            const int k = ((lane >> 4) << 3) + j;
            const int kw = k >> 2, ci = k & 3;
            const int n = nt * 16 + (lane & 15);
            float v = (ci < 3 && kw < 7) ? w1[(size_t)((kh * 7 + kw) * 3 + ci) * 64 + n] : 0.f;
            wp1[e] = __float2bfloat16(v);
        } else if (e < 88064) {
            const int e2 = e - 14336;
            const int j = e2 & 7, lane = (e2 >> 3) & 63, nt = (e2 >> 9) & 7, ks = (e2 >> 12) & 1, tap = e2 >> 13;
            const int ci = ks * 32 + ((lane >> 4) << 3) + j;
            const int n  = nt * 16 + (lane & 15);
            wp2[e2] = __float2bfloat16(w2[(size_t)(tap * 64 + ci) * 128 + n]);
        } else {
            const int e3 = e - 88064;
            const int j = e3 & 7, lane = (e3 >> 3) & 63, nt = (e3 >> 9) & 15, ks = (e3 >> 13) & 3, tap = e3 >> 15;
            const int ci = ks * 32 + ((lane >> 4) << 3) + j;
            const int n  = nt * 16 + (lane & 15);
            wp3[e3] = __float2bfloat16(w3[(size_t)(tap * 128 + ci) * 256 + n]);
        }
    }
}

// ---------- fused conv1+conv2 (256 thr, 4 waves; phase-1 kh-interleaved across 3 rows) ----------
// Phase 1: one kh loop; B[kh] loaded once, reused by 3 rows x 2 mt (6 independent A-loads,
//   24 MFMA per step; serial depth 7). launch_bounds (256,2): acc1 96 VGPR stays in regs.
//   Rows written to LDS in conv2's swizzled A-layout:
//   byte = px*128 + ((jg ^ ((px>>1)&7))*16 + (n&7)*2), jg=n>>3. px128 / row128 zeroed.
// Phase 2: 18-slice conv2 K-loop; wave = 4 mtiles x 2 ntiles, A from LDS, B=w2p from L2.
__global__ __launch_bounds__(256, 2) void k_conv12(const __hip_bfloat16* __restrict__ pv,
                                                   const __hip_bfloat16* __restrict__ w1p,
                                                   const float* __restrict__ b1,
                                                   const __hip_bfloat16* __restrict__ w2p,
                                                   const float* __restrict__ b2,
                                                   __hip_bfloat16* __restrict__ c2p)
{
    __shared__ __align__(16) char lc1[3 * 16512];    // 49,536 B: 3 c1 rows [129px][128B]

    const int xcd = blockIdx.x & 7;
    const int sub = blockIdx.x >> 3;       // 0..383
    const int bt  = xcd * 6 + sub / 64;
    const int oy2 = sub % 64;
    const int tid = threadIdx.x;
    const int w   = tid >> 6;
    const int l   = tid & 63;
    const int li  = l & 15, lh = l >> 4;

    const short* pvS = (const short*)pv;
    const short* w1S = (const short*)w1p;

    // ---- phase 1: 3 conv1 rows, kh-interleaved ----
    const int r0 = oy2 * 2;
    f32x4 acc1[3][2][4];
#pragma unroll
    for (int row = 0; row < 3; ++row)
#pragma unroll
        for (int m = 0; m < 2; ++m)
#pragma unroll
            for (int n = 0; n < 4; ++n) acc1[row][m][n] = (f32x4){0.f, 0.f, 0.f, 0.f};

    const int ox0 = w * 32;
#pragma unroll
    for (int kh = 0; kh < 7; ++kh) {
        bf16x8 bw[4];
#pragma unroll
        for (int nt = 0; nt < 4; ++nt)
            bw[nt] = *reinterpret_cast<const bf16x8*>(w1S + ((size_t)(kh * 4 + nt) * 64 + l) * 8);
#pragma unroll
        for (int row = 0; row < 3; ++row) {
            const int r   = r0 + row;
            const int rcl = (r < 128) ? r : 127;       // clamp (row 128 overwritten with zeros)
            const short* rbase = pvS + (size_t)(bt * 261 + rcl * 2 + kh) * 1056;
#pragma unroll
            for (int mt = 0; mt < 2; ++mt) {
                bf16x8 a = *reinterpret_cast<const bf16x8*>(
                    rbase + 8 * (ox0 + mt * 16 + li + lh));
#pragma unroll
                for (int nt = 0; nt < 4; ++nt)
                    acc1[row][mt][nt] = __builtin_amdgcn_mfma_f32_16x16x32_bf16(
                        a, bw[nt], acc1[row][mt][nt], 0, 0, 0);
            }
        }
    }

    // epilogue: acc -> LDS (swizzled); pad rows/px zeroed
#pragma unroll
    for (int row = 0; row < 3; ++row) {
        const int r = r0 + row;
        char* rowbuf = lc1 + row * 16512;
        if (r < 128) {                     // block-uniform
#pragma unroll
            for (int mt = 0; mt < 2; ++mt) {
#pragma unroll
                for (int nt = 0; nt < 4; ++nt) {
                    const int n = nt * 16 + li;
                    const float bias = b1[n];
                    const int jg = nt * 2 + (li >> 3);
#pragma unroll
                    for (int r4 = 0; r4 < 4; ++r4) {
                        const int px = ox0 + mt * 16 + lh * 4 + r4;
                        const float v = fmaxf(acc1[row][mt][nt][r4] * (1.f / 255.f) + bias, 0.f);
                        *reinterpret_cast<unsigned short*>(
                            rowbuf + px * 128 + ((jg ^ ((px >> 1) & 7)) * 16 + (li & 7) * 2)) = bfr(v);
                    }
                }
            }
            if (tid < 8)                   // zero pad px 128 (swizzle identity)
                *reinterpret_cast<uint4*>(rowbuf + 128 * 128 + tid * 16) = (uint4){0u, 0u, 0u, 0u};
        } else {                           // r == 128: SAME-pad zero row (only oy2==63)
#pragma unroll
            for (int it = 0; it < 5; ++it) {
                const int g = it * 256 + tid;
                if (g < 1032)
                    *reinterpret_cast<uint4*>(rowbuf + (size_t)g * 16) = (uint4){0u, 0u, 0u, 0u};
            }
        }
    }
    __syncthreads();                       // only barrier in the kernel

    // ---- phase 2: conv2 K-loop (A from LDS, B from global L2) ----
    const int ntb = w * 2;
    f32x4 acc[4][2];
#pragma unroll
    for (int i = 0; i < 4; ++i) {
        acc[i][0] = (f32x4){0.f, 0.f, 0.f, 0.f};
        acc[i][1] = (f32x4){0.f, 0.f, 0.f, 0.f};
    }

    const char* wB = (const char*)w2p;
#pragma unroll
    for (int s = 0; s < 18; ++s) {
        const int tap = s >> 1, ks = s & 1;
        const int kh = tap / 3, kw = tap % 3;

        bf16x8 bf[2];
#pragma unroll
        for (int j = 0; j < 2; ++j)
            bf[j] = *reinterpret_cast<const bf16x8*>(wB + ((size_t)s * 8 + ntb + j) * 1024 + l * 16);

        const char* Ar = lc1 + kh * 16512;
        bf16x8 af[4];
#pragma unroll
        for (int i = 0; i < 4; ++i) {
            const int ix  = (i * 16 + li) * 2 + kw;
            const int off = ((ks * 4 + lh) ^ ((ix >> 1) & 7)) * 16;
            af[i] = *reinterpret_cast<const bf16x8*>(Ar + (size_t)ix * 128 + off);
        }

#pragma unroll
        for (int i = 0; i < 4; ++i)
#pragma unroll
            for (int j = 0; j < 2; ++j)
                acc[i][j] = __builtin_amdgcn_mfma_f32_16x16x32_bf16(af[i], bf[j], acc[i][j], 0, 0, 0);
    }

    __hip_bfloat16* ob = c2p + (size_t)(bt * 65 + oy2) * 65 * 128;
#pragma unroll
    for (int i = 0; i < 4; ++i) {
        const int ox = i * 16 + lh * 4;
#pragma unroll
        for (int j = 0; j < 2; ++j) {
            const int n = (ntb + j) * 16 + li;
            const float bv = b2[n];
#pragma unroll
            for (int r4 = 0; r4 < 4; ++r4) {
                const float v = fmaxf(acc[i][j][r4] + bv, 0.f);
                ob[(size_t)(ox + r4) * 128 + n] = __float2bfloat16(v);
            }
        }
    }
}

// ---------- row-resident conv3 (barrier-free K-loop, dup-minimized wave split) ----------
template<int CIN, int COUT, int OW, int IW, int ORS, int NTHR, int WMT, int WNT, int MINW>
__global__ __launch_bounds__(NTHR, MINW) void k_convr(const __hip_bfloat16* __restrict__ in,
                                                      const __hip_bfloat16* __restrict__ wp,
                                                      const float* __restrict__ bias,
                                                      __hip_bfloat16* __restrict__ out)
{
    constexpr int KSN  = CIN / 32;
    constexpr int NSL  = 9 * KSN;
    constexpr int NTT  = COUT / 16;
    constexpr int GPX  = CIN / 8;          // 16B granules per pixel
    constexpr int ROWG = IW * GPX;         // granules per input row
    constexpr int RST  = ROWG * 16;        // LDS row stride (bytes)
    constexpr int TOT  = 3 * ROWG;
    constexpr int SIT  = (TOT + NTHR - 1) / NTHR;

    __shared__ char lbuf[3 * RST];

    const int bid = blockIdx.x;
    const int xcd = bid & 7;
    const int sub = bid >> 3;
    const int bt  = xcd * 6 + sub / OW;
    const int oy  = sub % OW;

    const int tid = threadIdx.x;
    const int w   = tid >> 6;
    const int l   = tid & 63;
    const int li  = l & 15, lh = l >> 4;
    const int ntb = w * WNT;

    const short* inS = (const short*)in;
    const size_t rb = (size_t)(bt * IW + oy * 2) * IW * CIN;
#pragma unroll
    for (int it = 0; it < SIT; ++it) {
        const int g = it * NTHR + tid;
        if (g < TOT) {
            const int r  = g / ROWG;
            const int rm = g - r * ROWG;
            const int px = rm / GPX;
            const int j  = rm - px * GPX;
            const int q  = j ^ ((px >> 1) & 7);
            __builtin_amdgcn_global_load_lds(
                (gv_t*)(inS + rb + (size_t)r * IW * CIN + px * CIN + q * 8),
                (sv_t*)(lbuf + (size_t)g * 16), 16, 0, 0);
        }
    }
    __syncthreads();

    f32x4 acc[WMT][WNT];
#pragma unroll
    for (int i = 0; i < WMT; ++i)
#pragma unroll
        for (int j = 0; j < WNT; ++j) acc[i][j] = (f32x4){0.f, 0.f, 0.f, 0.f};

    const char* wB = (const char*)wp;

#pragma unroll
    for (int s = 0; s < NSL; ++s) {
        const int tap = s / KSN, ks = s % KSN;
        const int kh = tap / 3, kw = tap % 3;

        bf16x8 bf[WNT];
#pragma unroll
        for (int j = 0; j < WNT; ++j)
            bf[j] = *reinterpret_cast<const bf16x8*>(wB + ((size_t)s * NTT + ntb + j) * 1024 + l * 16);

        const char* Ar = lbuf + kh * RST;
        bf16x8 af[WMT];
#pragma unroll
        for (int i = 0; i < WMT; ++i) {
            const int ix  = (i * 16 + li) * 2 + kw;
            const int off = ((ks * 4 + lh) ^ ((ix >> 1) & 7)) * 16;
            af[i] = *reinterpret_cast<const bf16x8*>(Ar + (size_t)ix * (CIN * 2) + off);
        }

#pragma unroll
        for (int i = 0; i < WMT; ++i)
#pragma unroll
            for (int j = 0; j < WNT; ++j)
                acc[i][j] = __builtin_amdgcn_mfma_f32_16x16x32_bf16(af[i], bf[j], acc[i][j], 0, 0, 0);
    }

    __hip_bfloat16* ob = out + (size_t)(bt * ORS + oy) * ORS * COUT;
#pragma unroll
    for (int i = 0; i < WMT; ++i) {
        const int ox = i * 16 + lh * 4;
#pragma unroll
        for (int j = 0; j < WNT; ++j) {
            const int n = (ntb + j) * 16 + li;
            const float bv = bias[n];
#pragma unroll
            for (int r = 0; r < 4; ++r) {
                const float v = fmaxf(acc[i][j][r] + bv, 0.f);
                ob[(size_t)(ox + r) * COUT + n] = __float2bfloat16(v);
            }
        }
    }
}

// ---------- bilinear query sampling -> q bf16 [1024,256] ----------
__global__ __launch_bounds__(256) void k_sample(const float* __restrict__ qp,
                                                const __hip_bfloat16* __restrict__ feat,
                                                __hip_bfloat16* __restrict__ q)
{
    const int bn = blockIdx.x;
    const int b  = bn >> 9;
    const float t3 = qp[bn * 3 + 0];
    const float yv = qp[bn * 3 + 1] * 31.f;
    const float xv = qp[bn * 3 + 2] * 31.f;
    int t = (int)(t3 * 23.f);
    t = min(max(t, 0), 23);
    int y0 = (int)floorf(yv); y0 = min(max(y0, 0), 31);
    const int y1 = min(y0 + 1, 31);
    int x0 = (int)floorf(xv); x0 = min(max(x0, 0), 31);
    const int x1 = min(x0 + 1, 31);
    const float wy1 = yv - (float)y0, wy0 = 1.f - wy1;
    const float wx1 = xv - (float)x0, wx0 = 1.f - wx1;

    const int c = threadIdx.x;
    const __hip_bfloat16* fb = feat + ((size_t)(b * 24 + t) * 1024) * 256;
    const float f00 = __bfloat162float(fb[(size_t)(y0 * 32 + x0) * 256 + c]);
    const float f01 = __bfloat162float(fb[(size_t)(y0 * 32 + x1) * 256 + c]);
    const float f10 = __bfloat162float(fb[(size_t)(y1 * 32 + x0) * 256 + c]);
    const float f11 = __bfloat162float(fb[(size_t)(y1 * 32 + x1) * 256 + c]);
    const float v = (f00 * wx0 + f01 * wx1) * wy0 + (f10 * wx0 + f11 * wx1) * wy1;
    q[(size_t)bn * 256 + c] = __float2bfloat16(v);
}

// ---------- correlation: LDS-staged MFMA + online softmax (128 positions / block) ----------
__global__ __launch_bounds__(256, 2) void k_corrm(const __hip_bfloat16* __restrict__ qb,
                                                  const __hip_bfloat16* __restrict__ featb,
                                                  float* __restrict__ pbuf)
{
    __shared__ short lbuf[2][8192];          // 2 x 16KB

    const int bid = blockIdx.x;
    const int xcd = bid & 7;
    const int sub = bid >> 3;
    const int grp = sub >> 5;
    const int prt = sub & 31;
    const int img = xcd * 6 + grp;
    const int bq  = img / 24, t = img % 24;
    const int nc  = prt & 3, ps = prt >> 2;

    const int tid = threadIdx.x;
    const int w   = tid >> 6;
    const int l   = tid & 63;
    const int li  = l & 15, lh = l >> 4;

    const short* qS = (const short*)qb;
    const short* fS = (const short*)featb + (size_t)img * 1024 * 256;
    const char*  tile0 = (const char*)(fS + (size_t)(ps * 128) * 256);

    const int q0 = nc * 128 + w * 32;
    bf16x8 aq[2][8];
#pragma unroll
    for (int mt = 0; mt < 2; ++mt)
#pragma unroll
        for (int ks = 0; ks < 8; ++ks)
            aq[mt][ks] = *reinterpret_cast<const bf16x8*>(
                qS + ((size_t)(bq * 512 + q0 + mt * 16 + li)) * 256 + ks * 32 + lh * 8);

    float m[2][4], s[2][4], sx[2][4], sy[2][4], dmx[2][4];
#pragma unroll
    for (int mt = 0; mt < 2; ++mt)
#pragma unroll
        for (int r = 0; r < 4; ++r) {
            m[mt][r] = -1e30f; s[mt][r] = 0.f; sx[mt][r] = 0.f; sy[mt][r] = 0.f; dmx[mt][r] = -1e30f;
        }

    bf16x8 stg[4];
#pragma unroll
    for (int i = 0; i < 4; ++i) {
        const int g = i * 256 + tid;
        const int pos = g >> 5, kb = (g & 31) * 16;
        stg[i] = *reinterpret_cast<const bf16x8*>(tile0 + (size_t)pos * 512 + kb);
    }
#pragma unroll
    for (int i = 0; i < 4; ++i) {
        const int g = i * 256 + tid;
        const int pos = g >> 5, kb = (g & 31) * 16;
        *reinterpret_cast<bf16x8*>((char*)&lbuf[0][0] + pos * 512 + (kb ^ ((pos & 7) << 4))) = stg[i];
    }
    __syncthreads();

#pragma unroll
    for (int st = 0; st < 4; ++st) {
        const int cur = st & 1;

        if (st < 3) {
            const char* tn = tile0 + (size_t)((st + 1) * 32) * 512;
#pragma unroll
            for (int i = 0; i < 4; ++i) {
                const int g = i * 256 + tid;
                const int pos = g >> 5, kb = (g & 31) * 16;
                stg[i] = *reinterpret_cast<const bf16x8*>(tn + (size_t)pos * 512 + kb);
            }
        }

        f32x4 acc[2][2];
#pragma unroll
        for (int mt = 0; mt < 2; ++mt)
#pragma unroll
            for (int pt = 0; pt < 2; ++pt) acc[mt][pt] = (f32x4){0.f, 0.f, 0.f, 0.f};

#pragma unroll
        for (int pt = 0; pt < 2; ++pt) {
            const int p = pt * 16 + li;
#pragma unroll
            for (int ks = 0; ks < 8; ++ks) {
                const int k = ks * 32 + lh * 8;
                bf16x8 bv = *reinterpret_cast<const bf16x8*>(&lbuf[cur][p * 256 + (k ^ ((p & 7) << 3))]);
                acc[0][pt] = __builtin_amdgcn_mfma_f32_16x16x32_bf16(aq[0][ks], bv, acc[0][pt], 0, 0, 0);
                acc[1][pt] = __builtin_amdgcn_mfma_f32_16x16x32_bf16(aq[1][ks], bv, acc[1][pt], 0, 0, 0);
            }
        }

        const float py = (float)(ps * 4 + st);
#pragma unroll
        for (int mt = 0; mt < 2; ++mt)
#pragma unroll
            for (int r = 0; r < 4; ++r) {
                const float v0 = acc[mt][0][r], v1 = acc[mt][1][r];
                float mx = fmaxf(v0, v1);
                mx = fmaxf(mx, __shfl_xor(mx, 1));
                mx = fmaxf(mx, __shfl_xor(mx, 2));
                mx = fmaxf(mx, __shfl_xor(mx, 4));
                mx = fmaxf(mx, __shfl_xor(mx, 8));
                dmx[mt][r] = fmaxf(dmx[mt][r], mx);
                const float mn = fmaxf(m[mt][r], mx * 0.625f);
                const float sc = __expf(m[mt][r] - mn);
                const float e0 = __expf(v0 * 0.625f - mn);
                const float e1 = __expf(v1 * 0.625f - mn);
                const float es = e0 + e1;
                s[mt][r]  = s[mt][r]  * sc + es;
                sx[mt][r] = sx[mt][r] * sc + es * (float)li + 16.f * e1;
                sy[mt][r] = sy[mt][r] * sc + es * py;
                m[mt][r] = mn;
            }

        if (st < 3) {
#pragma unroll
            for (int i = 0; i < 4; ++i) {
                const int g = i * 256 + tid;
                const int pos = g >> 5, kb = (g & 31) * 16;
                *reinterpret_cast<bf16x8*>((char*)&lbuf[cur ^ 1][0] + pos * 512 + (kb ^ ((pos & 7) << 4))) = stg[i];
            }
            __syncthreads();
        }
    }

#pragma unroll
    for (int mt = 0; mt < 2; ++mt)
#pragma unroll
        for (int r = 0; r < 4; ++r) {
#pragma unroll
            for (int off = 1; off < 16; off <<= 1) {
                s[mt][r]  += __shfl_xor(s[mt][r],  off);
                sx[mt][r] += __shfl_xor(sx[mt][r], off);
                sy[mt][r] += __shfl_xor(sy[mt][r], off);
            }
        }

    if (li == 0) {
#pragma unroll
        for (int mt = 0; mt < 2; ++mt)
#pragma unroll
            for (int r = 0; r < 4; ++r) {
                const int n = q0 + mt * 16 + lh * 4 + r;
                const int bnt = (bq * 512 + n) * 24 + t;
                const int pi = ps * 24576 + bnt;
                pbuf[pi]                = m[mt][r];
                pbuf[196608 + pi]       = s[mt][r];
                pbuf[393216 + pi]       = sx[mt][r];
                pbuf[589824 + pi]       = sy[mt][r];
                pbuf[786432 + pi]       = dmx[mt][r];
            }
    }
}

// ---------- merge 8 position-chunk partials -> outputs ----------
__global__ __launch_bounds__(256) void k_merge(const float* __restrict__ pbuf,
                                               float* __restrict__ outp)
{
    const int i = blockIdx.x * 256 + threadIdx.x;
    float M = -1e30f, D = -1e30f;
#pragma unroll
    for (int ps = 0; ps < 8; ++ps) {
        M = fmaxf(M, pbuf[ps * 24576 + i]);
        D = fmaxf(D, pbuf[786432 + ps * 24576 + i]);
    }
    float s = 0.f, sx = 0.f, sy = 0.f;
#pragma unroll
    for (int ps = 0; ps < 8; ++ps) {
        const int pi = ps * 24576 + i;
        const float wgt = __expf(pbuf[pi] - M);
        s  += pbuf[196608 + pi] * wgt;
        sx += pbuf[393216 + pi] * wgt;
        sy += pbuf[589824 + pi] * wgt;
    }
    const float inv = 8.f / s;
    outp[i * 2 + 0] = sx * inv;
    outp[i * 2 + 1] = sy * inv;
    outp[49152 + i] = 1.f / (1.f + __expf(D * 0.0625f));
}

extern "C" void kernel_launch(void* const* d_in, const int* in_sizes, int n_in,
                              void* d_out, int out_size, void* d_ws, size_t ws_size,
                              hipStream_t stream)
{
    const float* video = (const float*)d_in[0];
    const float* qp    = (const float*)d_in[1];
    const float* w1    = (const float*)d_in[2];
    const float* b1    = (const float*)d_in[3];
    const float* w2    = (const float*)d_in[4];
    const float* b2    = (const float*)d_in[5];
    const float* w3    = (const float*)d_in[6];
    const float* b3    = (const float*)d_in[7];
    float* out = (float*)d_out;

    char* wsb = (char*)d_ws;
    __hip_bfloat16* c2p   = (__hip_bfloat16*)(wsb);                    //  51,916,800 B
    __hip_bfloat16* pv    = (__hip_bfloat16*)(wsb + 51916800ull);      //  26,459,136 B (dead after conv12)
    __hip_bfloat16* featb = (__hip_bfloat16*)(wsb + 51916800ull);      //  25,165,824 B
    __hip_bfloat16* qbuf  = (__hip_bfloat16*)(wsb + 78375936ull);      //     524,288 B
    __hip_bfloat16* w1p   = (__hip_bfloat16*)(wsb + 78900224ull);      //      28,672 B
    __hip_bfloat16* w2p   = (__hip_bfloat16*)(wsb + 78928896ull);      //     147,456 B
    __hip_bfloat16* w3p   = (__hip_bfloat16*)(wsb + 79076352ull);      //     589,824 B
    float*          pbuf  = (float*)(wsb + 79666176ull);               //   3,932,160 B

    k_prep   <<<dim3(17870), dim3(256), 0, stream>>>(
                  video, w1, w2, w3, pv, (unsigned short*)c2p, w1p, w2p, w3p);
    k_conv12 <<<dim3(3072),  dim3(256), 0, stream>>>(pv, w1p, b1, w2p, b2, c2p);
    k_convr<128, 256, 32, 65, 32, 512, 2, 2, 6><<<dim3(1536), dim3(512), 0, stream>>>(c2p, w3p, b3, featb);
    k_sample <<<dim3(1024),  dim3(256), 0, stream>>>(qp, featb, qbuf);
    k_corrm  <<<dim3(1536),  dim3(256), 0, stream>>>(qbuf, featb, pbuf);
    k_merge  <<<dim3(96),    dim3(256), 0, stream>>>(pbuf, out);
}